// Round 1
// 580.199 us; speedup vs baseline: 1.3439x; 1.3439x over previous
//
#include <hip/hip_runtime.h>
#include <cstdint>
#include <cstddef>

#define BATCH 1024
#define FEAT 128
#define NCLS 100000
#define MARGIN 0.1f
#define SCALARV 1.0f
#define EPSV 1e-12f

// N tile = 160 (100000 = 625 * 160, exact). Block = 256 threads = 4 waves in 2x2.
// Each wave: 64 rows x 80 cols = 4 mi-tiles x 5 ni-tiles of 16x16 MFMA.
#define BN 160
#define NBLOCKS 625

typedef __bf16 bf16x8 __attribute__((ext_vector_type(8)));
typedef float floatx4 __attribute__((ext_vector_type(4)));

// ws layout (bytes):
//   [0, 262144)        x_bf16 : 1024 x 128 bf16 (ushort bits)
//   [262144, 266240)   sumexp : f32[1024]
//   [266240, 270336)   tlogit : f32[1024]
#define WS_X 0
#define WS_SUMEXP 262144
#define WS_TLOGIT 266240

static __device__ __forceinline__ unsigned short f2bf(float f) {
    // round-to-nearest-even fp32 -> bf16 (inputs are finite normals; no NaN path)
    uint32_t u = __float_as_uint(f);
    u += 0x7FFFu + ((u >> 16) & 1u);
    return (unsigned short)(u >> 16);
}

// Kernel 1: L2-normalize inputs -> bf16 in ws; zero the sumexp accumulators.
__global__ __launch_bounds__(256) void k_normalize(const float* __restrict__ in,
                                                   unsigned short* __restrict__ xb,
                                                   float* __restrict__ sumexp) {
    if (blockIdx.x == 0) {
        for (int i = threadIdx.x; i < BATCH; i += 256) sumexp[i] = 0.0f;
    }
    const int wid = threadIdx.x >> 6;
    const int lane = threadIdx.x & 63;
    const int row = blockIdx.x * 4 + wid;   // one wave per row
    const float2 v = reinterpret_cast<const float2*>(in + (size_t)row * FEAT)[lane];
    float ss = v.x * v.x + v.y * v.y;
#pragma unroll
    for (int m = 1; m <= 32; m <<= 1) ss += __shfl_xor(ss, m, 64);
    const float scale = 1.0f / (sqrtf(ss) + EPSV);
    const unsigned int lo = f2bf(v.x * scale);
    const unsigned int hi = f2bf(v.y * scale);
    reinterpret_cast<unsigned int*>(xb + (size_t)row * FEAT)[lane] = lo | (hi << 16);
}

// Kernel 2: bf16 MFMA GEMM (C = x @ lut^T), margin at target, write logits,
// accumulate per-row sum(exp(logit)) and capture logit_target.
//
// SWAPPED-OPERAND MFMA: we issue mfma(lut_frag, x_frag, acc).  Both operand
// layouts are "idx = lane&15, k = (lane>>4)*8 + j", so the same register
// contents serve as A or B.  With lut as the A operand, the 16x16 D tile is
// D[n_local = (lane>>4)*4 + reg][m_local = lane&15]:
//   each lane's 4 acc regs = 4 CONSECUTIVE logits columns of ONE row
//   -> aligned float4 stores, 64B contiguous per row per instruction,
//   -> adjacent ni instructions extend the same row (L2 assembles full lines).
__global__ __launch_bounds__(256, 2) void k_gemm(const unsigned short* __restrict__ xb,
                                                 const float* __restrict__ lut,
                                                 const int* __restrict__ targets,
                                                 float* __restrict__ out_logits,
                                                 float* __restrict__ sumexp,
                                                 float* __restrict__ tlogit) {
    const int n0 = blockIdx.x * BN;
    const int tid = threadIdx.x;
    const int wid = tid >> 6;
    const int lane = tid & 63;
    const int q = lane >> 4;      // quad: 0..3
    const int c = lane & 15;      // 0..15
    const int wm = wid >> 1;      // 0..1 : wave row-half
    const int wn = wid & 1;       // 0..1 : wave col-half

    // --- Load lut fragments once, fp32 -> bf16 in flight (nontemporal: lut is
    // read-once per block; keep L2 for xb and the logits write stream).
    // Fragment layout: idx n = lane&15 (row of lut tile), k = q*8 + j.
    bf16x8 bfrag[5][4];
#pragma unroll
    for (int ni = 0; ni < 5; ++ni) {
        const int nrow = n0 + wn * 80 + ni * 16 + c;
        const float* bp = lut + (size_t)nrow * FEAT;
#pragma unroll
        for (int ks = 0; ks < 4; ++ks) {
            const int k = ks * 32 + q * 8;
            const floatx4 f0 = __builtin_nontemporal_load(
                reinterpret_cast<const floatx4*>(bp + k));
            const floatx4 f1 = __builtin_nontemporal_load(
                reinterpret_cast<const floatx4*>(bp + k) + 1);
            union { unsigned short s[8]; bf16x8 v; } t;
            t.s[0] = f2bf(f0[0]); t.s[1] = f2bf(f0[1]);
            t.s[2] = f2bf(f0[2]); t.s[3] = f2bf(f0[3]);
            t.s[4] = f2bf(f1[0]); t.s[5] = f2bf(f1[1]);
            t.s[6] = f2bf(f1[2]); t.s[7] = f2bf(f1[3]);
            bfrag[ni][ks] = t.v;
        }
    }

    // --- Loop over all 8 M-tiles of 128 rows, reusing bfrag.
    for (int miter = 0; miter < 8; ++miter) {
        const int m0 = miter * 128;
        floatx4 acc[4][5];
#pragma unroll
        for (int mi = 0; mi < 4; ++mi)
#pragma unroll
            for (int ni = 0; ni < 5; ++ni) {
                floatx4 z = {0.0f, 0.0f, 0.0f, 0.0f};
                acc[mi][ni] = z;
            }

#pragma unroll
        for (int ks = 0; ks < 4; ++ks) {
            bf16x8 af[4];
#pragma unroll
            for (int mi = 0; mi < 4; ++mi) {
                const int mrow = m0 + wm * 64 + mi * 16 + c;
                af[mi] = *reinterpret_cast<const bf16x8*>(
                    xb + (size_t)mrow * FEAT + ks * 32 + q * 8);
            }
#pragma unroll
            for (int mi = 0; mi < 4; ++mi)
#pragma unroll
                for (int ni = 0; ni < 5; ++ni)
                    acc[mi][ni] = __builtin_amdgcn_mfma_f32_16x16x32_bf16(
                        bfrag[ni][ks], af[mi], acc[mi][ni], 0, 0, 0);
        }

        // --- Epilogue: margin, float4 stores through L2, per-row sum(exp).
        // Lane owns row m = m0 + wm*64 + mi*16 + c, cols nb..nb+3 per (ni).
#pragma unroll
        for (int mi = 0; mi < 4; ++mi) {
            const int row = m0 + wm * 64 + mi * 16 + c;
            const int tgt = targets[row];     // 4 lanes same addr: broadcast
            float* rowp = out_logits + (size_t)row * NCLS;
            float part = 0.0f;
#pragma unroll
            for (int ni = 0; ni < 5; ++ni) {
                const int nb = n0 + wn * 80 + ni * 16 + q * 4;
                floatx4 vv = acc[mi][ni];
#pragma unroll
                for (int r = 0; r < 4; ++r) {
                    float v = vv[r];
                    const bool hit = (nb + r == tgt);
                    if (hit) v -= MARGIN;
                    v *= SCALARV;
                    if (hit) tlogit[row] = v;
                    vv[r] = v;
                    part += __expf(v);
                }
                *reinterpret_cast<floatx4*>(rowp + nb) = vv;   // 16B aligned
            }
            // reduce the row partial over the 4 quads (lanes c, c+16, c+32, c+48)
            part += __shfl_xor(part, 16, 64);
            part += __shfl_xor(part, 32, 64);
            if (q == 0) atomicAdd(&sumexp[row], part);
        }
    }
}

// Kernel 3: loss = mean(log(sumexp[row]) - tlogit[row]); single block.
__global__ __launch_bounds__(1024) void k_loss(const float* __restrict__ sumexp,
                                               const float* __restrict__ tlogit,
                                               float* __restrict__ out) {
    __shared__ float wsum[16];
    const int tid = threadIdx.x;
    float v = logf(sumexp[tid]) - tlogit[tid];
#pragma unroll
    for (int m = 1; m <= 32; m <<= 1) v += __shfl_xor(v, m, 64);
    if ((tid & 63) == 0) wsum[tid >> 6] = v;
    __syncthreads();
    if (tid < 64) {
        float t = (tid < 16) ? wsum[tid] : 0.0f;
#pragma unroll
        for (int m = 1; m <= 8; m <<= 1) t += __shfl_xor(t, m, 64);
        if (tid == 0) out[0] = t * (1.0f / BATCH);
    }
}

extern "C" void kernel_launch(void* const* d_in, const int* in_sizes, int n_in,
                              void* d_out, int out_size, void* d_ws, size_t ws_size,
                              hipStream_t stream) {
    const float* inputs = (const float*)d_in[0];
    const int* targets = (const int*)d_in[1];
    const float* lut = (const float*)d_in[2];

    float* out = (float*)d_out;            // out[0] = loss, out+1 = logits [1024,100000]
    char* ws = (char*)d_ws;
    unsigned short* xb = (unsigned short*)(ws + WS_X);
    float* sumexp = (float*)(ws + WS_SUMEXP);
    float* tlogit = (float*)(ws + WS_TLOGIT);

    k_normalize<<<BATCH / 4, 256, 0, stream>>>(inputs, xb, sumexp);
    k_gemm<<<NBLOCKS, 256, 0, stream>>>(xb, lut, targets, out + 1, sumexp, tlogit);
    k_loss<<<1, 1024, 0, stream>>>(sumexp, tlogit, out);
}